// Round 10
// baseline (3448.380 us; speedup 1.0000x reference)
//
#include <hip/hip_runtime.h>

#define NT 512   // timesteps
#define FB 128   // feature bins
#define HD 256   // L1 == L2 hidden
#define NC 10
#define NG 64    // groups
#define GR 4     // batch rows per group

typedef __attribute__((ext_vector_type(8))) short bf16x8;
typedef __attribute__((ext_vector_type(4))) float f32x4;
typedef __attribute__((ext_vector_type(4))) unsigned u32x4;
typedef __attribute__((ext_vector_type(2))) unsigned u32x2;

static __device__ __forceinline__ short f2bf(float f){
  union { float f; unsigned u; } v; v.f = f;
  return (short)((v.u + 0x7fffu + ((v.u >> 16) & 1u)) >> 16);  // RNE
}
static __device__ __forceinline__ float bf2f(short h){
  union { unsigned u; float f; } v; v.u = ((unsigned)(unsigned short)h) << 16;
  return v.f;
}
static __device__ __forceinline__ float quantw(float w){
  return fminf(fmaxf(rintf(w * 8.0f) * 0.125f, -1.0f), 1.0f);  // exact in bf16
}
static __device__ __forceinline__ bf16x8 loadqw8(const float* __restrict__ p){
  bf16x8 v;
#pragma unroll
  for (int j = 0; j < 8; ++j) v[j] = f2bf(quantw(p[j]));
  return v;
}
static __device__ __forceinline__ void split8(f32x4 a, f32x4 b, bf16x8& hi, bf16x8& lo){
  float v0[4] = {a[0],a[1],a[2],a[3]}, v1[4] = {b[0],b[1],b[2],b[3]};
#pragma unroll
  for (int j = 0; j < 4; ++j){
    short h = f2bf(v0[j]); hi[j] = h; lo[j] = f2bf(v0[j] - bf2f(h));
  }
#pragma unroll
  for (int j = 0; j < 4; ++j){
    short h = f2bf(v1[j]); hi[4+j] = h; lo[4+j] = f2bf(v1[j] - bf2f(h));
  }
}

// ---- epoch-in-band messaging over sc1 (memory-side coherent point) ----
// element = 2 u32 words: (hi_bf16<<16)|epoch, (lo_bf16<<16)|epoch.
// Word-atomic visibility: epoch match in a word guarantees its payload.
static __device__ __forceinline__ void st_msg(unsigned* p, short hb, short lb, unsigned ep){
  u32x2 w;
  w[0] = (((unsigned)(unsigned short)hb) << 16) | ep;
  w[1] = (((unsigned)(unsigned short)lb) << 16) | ep;
  asm volatile("global_store_dwordx2 %0, %1, off sc1" :: "v"(p), "v"(w) : "memory");
}
// gather 8 elements (64 B), retry until all 16 epoch fields match
static __device__ __forceinline__ void gather8(const unsigned* p, unsigned ep, bf16x8& hv, bf16x8& lv){
  u32x4 a, b, c, d;
  for (;;){
    asm volatile("global_load_dwordx4 %0, %4, off sc1\n\t"
                 "global_load_dwordx4 %1, %4, off offset:16 sc1\n\t"
                 "global_load_dwordx4 %2, %4, off offset:32 sc1\n\t"
                 "global_load_dwordx4 %3, %4, off offset:48 sc1\n\t"
                 "s_waitcnt vmcnt(0)"
                 : "=&v"(a), "=&v"(b), "=&v"(c), "=&v"(d) : "v"(p) : "memory");
    unsigned m = (a[0]^ep)|(a[1]^ep)|(a[2]^ep)|(a[3]^ep)
               | (b[0]^ep)|(b[1]^ep)|(b[2]^ep)|(b[3]^ep)
               | (c[0]^ep)|(c[1]^ep)|(c[2]^ep)|(c[3]^ep)
               | (d[0]^ep)|(d[1]^ep)|(d[2]^ep)|(d[3]^ep);
    if ((m & 0xffffu) == 0u) break;
  }
  hv[0]=(short)(a[0]>>16); lv[0]=(short)(a[1]>>16);
  hv[1]=(short)(a[2]>>16); lv[1]=(short)(a[3]>>16);
  hv[2]=(short)(b[0]>>16); lv[2]=(short)(b[1]>>16);
  hv[3]=(short)(b[2]>>16); lv[3]=(short)(b[3]>>16);
  hv[4]=(short)(c[0]>>16); lv[4]=(short)(c[1]>>16);
  hv[5]=(short)(c[2]>>16); lv[5]=(short)(c[3]>>16);
  hv[6]=(short)(d[0]>>16); lv[6]=(short)(d[1]>>16);
  hv[7]=(short)(d[2]>>16); lv[7]=(short)(d[3]>>16);
}

// 512 blocks x 256 threads, 2 blocks/CU (TLP hides exchange latency).
// gp = bid>>3 (contiguous 8-block groups, R6-proven co-resident at 2/CU),
// sb = bid&7. Each block: 32 h-dims (slice sb) for GR=4 batch rows; blocks
// sb<GR also own the head for batch row gp*GR+sb.
// Single-MFMA hi|lo (R6): B-tile rows 0-3 = hi, 8-11 = lo, others zero.
// Epoch-fused exchange + deferred h2 gather + 2 slots (R8/R9-proven).
__global__ __launch_bounds__(256, 2)
void egru_persistent(const float* __restrict__ xg,
                     const float* __restrict__ h1ig, const float* __restrict__ h2ig,
                     const float* __restrict__ W1g, const float* __restrict__ b1g,
                     const float* __restrict__ W2g, const float* __restrict__ b2g,
                     const float* __restrict__ W3g, const float* __restrict__ b3g,
                     const float* __restrict__ W4g, const float* __restrict__ b4g,
                     float* __restrict__ outg, float* __restrict__ wsf)
{
  const int tid = threadIdx.x;
  const int gp  = blockIdx.x >> 3;   // group 0..63
  const int sb  = blockIdx.x & 7;    // slice 0..7
  const int wv  = tid >> 6;          // wave 0..3
  const int ln  = tid & 15;          // MFMA frag m/n index
  const int lk  = (tid >> 4) & 3;    // MFMA frag k-subgroup
  const int rz  = sb * 32;           // slice's h-dim base

  __shared__ __align__(16) short in1[16*384];   // k<128 x(t), k>=128 h1; rows 0-3 hi, 8-11 lo
  __shared__ __align__(16) short in2[16*512];   // k<256 h1(t), k>=256 h2; rows 0-3 hi, 8-11 lo
  __shared__ float aldsA[64][17];               // L1 raw MFMA out
  __shared__ float aldsB[64][17];               // L2 raw MFMA out
  __shared__ float h1own[32][GR];               // fp32 master of own slice [dim][row]
  __shared__ float h2own[32][GR];
  __shared__ float h3p[128], h3q[128], h3row[128];
  __shared__ float ytmp[16];
  __shared__ float W4L[10*130];
  __shared__ float b1s[64], b2s[64], b3L[128], b4L[10];

  // workspace (u32): h1buf 2 slots x [NG][GR][HD] x 2 words @0 (1 MiB),
  //                  h2buf 2 slots @ +262144 u32 (1 MiB). memset-zeroed per launch.
  unsigned* h1buf = reinterpret_cast<unsigned*>(wsf);
  unsigned* h2buf = h1buf + 262144;

  // ---- resident weight fragments (A-operand; quantized weights exact in bf16) ----
  bf16x8 w1f[12], w2f[16], w3f[2][8];
  {
    const int arow = (wv < 2) ? (rz + wv*16 + ln) : (256 + rz + (wv-2)*16 + ln);
#pragma unroll
    for (int ks = 0; ks < 12; ++ks) w1f[ks] = loadqw8(W1g + arow*384 + ks*32 + lk*8);
#pragma unroll
    for (int ks = 0; ks < 16; ++ks) w2f[ks] = loadqw8(W2g + arow*512 + ks*32 + lk*8);
#pragma unroll
    for (int tl = 0; tl < 2; ++tl)
#pragma unroll
      for (int ks = 0; ks < 8; ++ks)
        w3f[tl][ks] = loadqw8(W3g + (wv*32 + tl*16 + ln)*256 + ks*32 + lk*8);
  }

  if (tid < 64){
    int grow = (tid < 32) ? (rz + tid) : (256 + rz + (tid - 32));
    b1s[tid] = b1g[grow];
    b2s[tid] = b2g[grow];
  }
  if (tid < 128) b3L[tid] = b3g[tid];
  if (tid < 10)  b4L[tid] = b4g[tid];
  for (int i = tid; i < 1280; i += 256)
    W4L[(i >> 7)*130 + (i & 127)] = quantw(W4g[i]);

  // zero B-tiles (rows 4-7 / 12-15 stay zero forever)
  for (int i = tid; i < 3072; i += 256) ((int*)in1)[i] = 0;
  for (int i = tid; i < 4096; i += 256) ((int*)in2)[i] = 0;
  __syncthreads();

  const int ur = tid >> 5, uc = tid & 31;   // (batch row, dim-chunk/dim) mapping; rows valid < GR
  if (tid < 128){
    bf16x8 hv, lv;
    const float* p1 = h1ig + (size_t)(gp*GR + ur)*HD + uc*8;
    split8(*(const f32x4*)p1, *(const f32x4*)(p1+4), hv, lv);
    *(bf16x8*)((char*)in1 + ur*768       + ((256 + uc*16) ^ ((ur&7)<<4))) = hv;
    *(bf16x8*)((char*)in1 + (ur+8)*768   + ((256 + uc*16) ^ ((ur&7)<<4))) = lv;
    *(bf16x8*)((char*)in2 + ur*1024      + ((      uc*16) ^ ((ur&7)<<4))) = hv;
    *(bf16x8*)((char*)in2 + (ur+8)*1024  + ((      uc*16) ^ ((ur&7)<<4))) = lv;
    const float* p2 = h2ig + (size_t)(gp*GR + ur)*HD + uc*8;
    split8(*(const f32x4*)p2, *(const f32x4*)(p2+4), hv, lv);
    *(bf16x8*)((char*)in2 + ur*1024      + ((512 + uc*16) ^ ((ur&7)<<4))) = hv;
    *(bf16x8*)((char*)in2 + (ur+8)*1024  + ((512 + uc*16) ^ ((ur&7)<<4))) = lv;
    h1own[uc][ur] = h1ig[(size_t)(gp*GR+ur)*HD + rz + uc];
    h2own[uc][ur] = h2ig[(size_t)(gp*GR+ur)*HD + rz + uc];
  }
  const int xr = tid >> 4, xf = tid & 15;   // x staging (rows >= GR unused)
  if (xr < GR){
    const float* px = xg + ((size_t)(gp*GR + xr)*NT + 0)*FB + xf*8;
    bf16x8 hv, lv;
    split8(*(const f32x4*)px, *(const f32x4*)(px+4), hv, lv);
    *(bf16x8*)((char*)in1 + xr*768     + ((xf*16) ^ ((xr&7)<<4))) = hv;
    *(bf16x8*)((char*)in1 + (xr+8)*768 + ((xf*16) ^ ((xr&7)<<4))) = lv;
  }
  __syncthreads();

  // ---- prologue: acc1 = L1(0) (single MFMA covers hi|lo) ----
  f32x4 acc1 = {0.f,0.f,0.f,0.f};
#pragma unroll
  for (int ks = 0; ks < 12; ++ks){
    bf16x8 bfr = *(bf16x8*)((char*)in1 + ln*768 + ((ks*64 + lk*16) ^ ((ln&7)<<4)));
    acc1 = __builtin_amdgcn_mfma_f32_16x16x32_bf16(w1f[ks], bfr, acc1, 0, 0, 0);
  }

  for (int t = 0; t < NT; ++t){
    unsigned* h1s = h1buf + (unsigned)(t & 1)*131072u + (unsigned)(gp*GR)*512u;       // write+read h1(t)
    unsigned* h2s = h2buf + (unsigned)(t & 1)*131072u + (unsigned)(gp*GR)*512u;       // write h2(t)
    unsigned* h2r = h2buf + (unsigned)((t + 1) & 1)*131072u + (unsigned)(gp*GR)*512u; // read h2(t-1)

    // ---- A1: finish h1(t); pack + store with epoch t+1 (no drain, no flag) ----
#pragma unroll
    for (int r4 = 0; r4 < 4; ++r4)
      aldsA[wv*16 + lk*4 + r4][ln] = acc1[r4];     // C/D: row=(lane>>4)*4+reg, col=lane&15
    __syncthreads();                                                   // BAR1
    if (tid < 128){
      float az = aldsA[uc][ur]    + aldsA[uc][ur+8]    + b1s[uc];      // hi-col + lo-col + bias
      float ac = aldsA[32+uc][ur] + aldsA[32+uc][ur+8] + b1s[32+uc];
      float z  = 0.5f*(az/(1.0f+fabsf(az)) + 1.0f);
      float cd = ac/(1.0f+fabsf(ac));
      float hn = z*h1own[uc][ur] + (1.0f - z)*cd;
      h1own[uc][ur] = hn;
      short hb = f2bf(hn), lb = f2bf(hn - bf2f(hb));
      st_msg(&h1s[ur*512 + (rz + uc)*2], hb, lb, (unsigned)(t+1));
    }

    // x(t+1) prefetch (plain cached loads; staged below)
    f32x4 xa = {0,0,0,0}, xb = {0,0,0,0};
    const bool pf = ((t+1) < NT) && (xr < GR);
    if (pf){
      const float* px = xg + ((size_t)(gp*GR + xr)*NT + (t+1))*FB + xf*8;
      xa = *(const f32x4*)px; xb = *(const f32x4*)(px+4);
    }

    // ---- A-window: gather h2(t-1) (epoch t) + stage x(t+1) ----
    if (t > 0 && tid < 128){
      bf16x8 hv, lv;
      gather8(&h2r[ur*512 + uc*16], (unsigned)t, hv, lv);
      *(bf16x8*)((char*)in2 + ur*1024     + ((512 + uc*16) ^ ((ur&7)<<4))) = hv;
      *(bf16x8*)((char*)in2 + (ur+8)*1024 + ((512 + uc*16) ^ ((ur&7)<<4))) = lv;
    }
    if (pf){
      bf16x8 hv, lv;
      split8(xa, xb, hv, lv);
      *(bf16x8*)((char*)in1 + xr*768     + ((xf*16) ^ ((xr&7)<<4))) = hv;
      *(bf16x8*)((char*)in1 + (xr+8)*768 + ((xf*16) ^ ((xr&7)<<4))) = lv;
    }
    __syncthreads();                                                   // BAR3

    // L2's h2(t-1) half
    f32x4 acc2 = {0.f,0.f,0.f,0.f};
#pragma unroll
    for (int ks = 8; ks < 16; ++ks){
      bf16x8 bfr = *(bf16x8*)((char*)in2 + ln*1024 + ((ks*64 + lk*16) ^ ((ln&7)<<4)));
      acc2 = __builtin_amdgcn_mfma_f32_16x16x32_bf16(w2f[ks], bfr, acc2, 0, 0, 0);
    }
    // head(t-1) for batch row gp*GR+sb (blocks sb<GR only; sb is block-uniform)
    if (t > 0 && sb < GR){
      f32x4 acc3a = {0,0,0,0}, acc3b = {0,0,0,0};
#pragma unroll
      for (int ks = 0; ks < 8; ++ks){
        bf16x8 bfr = *(bf16x8*)((char*)in2 + ln*1024 + ((512 + ks*64 + lk*16) ^ ((ln&7)<<4)));
        acc3a = __builtin_amdgcn_mfma_f32_16x16x32_bf16(w3f[0][ks], bfr, acc3a, 0, 0, 0);
        acc3b = __builtin_amdgcn_mfma_f32_16x16x32_bf16(w3f[1][ks], bfr, acc3b, 0, 0, 0);
      }
      if (ln == sb){
#pragma unroll
        for (int r4 = 0; r4 < 4; ++r4){
          int d0 = wv*32 + lk*4 + r4;
          h3p[d0] = acc3a[r4]; h3p[d0+16] = acc3b[r4];
        }
      }
      if (ln == sb + 8){
#pragma unroll
        for (int r4 = 0; r4 < 4; ++r4){
          int d0 = wv*32 + lk*4 + r4;
          h3q[d0] = acc3a[r4]; h3q[d0+16] = acc3b[r4];
        }
      }
      __syncthreads();                                                 // BAR4 (sb<GR blocks)
      if (tid < 128) h3row[tid] = fmaxf(h3p[tid] + h3q[tid] + b3L[tid], 0.0f);
      __syncthreads();                                                 // BAR5
      if (wv == 0){                                                    // L4: 4 lanes per class
        const int l = tid, c = l >> 2, kq = l & 3;
        float p = 0.f;
        if (c < 10){
          const float* wr = &W4L[c*130 + kq*32];
          const float* hr = &h3row[kq*32];
#pragma unroll
          for (int k = 0; k < 32; ++k) p += wr[k]*hr[k];
        }
        p += __shfl_xor(p, 1, 4);
        p += __shfl_xor(p, 2, 4);
        if (c < 10 && kq == 0) ytmp[c] = p + b4L[c];
        asm volatile("s_waitcnt lgkmcnt(0)" ::: "memory");
        float yv = (l < 10) ? ytmp[l] : -INFINITY;
        float mx = yv;
#pragma unroll
        for (int off = 1; off < 16; off <<= 1)
          mx = fmaxf(mx, __shfl_xor(mx, off, 16));
        float ex = (l < 10) ? expf(yv - mx) : 0.0f;
        float sm = ex;
#pragma unroll
        for (int off = 1; off < 16; off <<= 1)
          sm += __shfl_xor(sm, off, 16);
        if (l < 10)
          outg[((size_t)(gp*GR + sb)*NT + (t-1))*NC + l] = yv - (mx + logf(sm));
      }
    }

    // ---- A2: gather h1(t) (epoch t+1) -> in1 k>=128, in2 k<256 ----
    if (tid < 128){
      bf16x8 hv, lv;
      gather8(&h1s[ur*512 + uc*16], (unsigned)(t+1), hv, lv);
      *(bf16x8*)((char*)in1 + ur*768      + ((256 + uc*16) ^ ((ur&7)<<4))) = hv;
      *(bf16x8*)((char*)in1 + (ur+8)*768  + ((256 + uc*16) ^ ((ur&7)<<4))) = lv;
      *(bf16x8*)((char*)in2 + ur*1024     + ((      uc*16) ^ ((ur&7)<<4))) = hv;
      *(bf16x8*)((char*)in2 + (ur+8)*1024 + ((      uc*16) ^ ((ur&7)<<4))) = lv;
    }
    __syncthreads();                                                   // BAR7

    // ---- B: L2's h1(t) half -> h2(t) ----
#pragma unroll
    for (int ks = 0; ks < 8; ++ks){
      bf16x8 bfr = *(bf16x8*)((char*)in2 + ln*1024 + ((ks*64 + lk*16) ^ ((ln&7)<<4)));
      acc2 = __builtin_amdgcn_mfma_f32_16x16x32_bf16(w2f[ks], bfr, acc2, 0, 0, 0);
    }
#pragma unroll
    for (int r4 = 0; r4 < 4; ++r4)
      aldsB[wv*16 + lk*4 + r4][ln] = acc2[r4];
    __syncthreads();                                                   // BAR8
    if (tid < 128){
      float az = aldsB[uc][ur]    + aldsB[uc][ur+8]    + b2s[uc];
      float ac = aldsB[32+uc][ur] + aldsB[32+uc][ur+8] + b2s[32+uc];
      float z  = 0.5f*(az/(1.0f+fabsf(az)) + 1.0f);
      float cd = ac/(1.0f+fabsf(ac));
      float hn = z*h2own[uc][ur] + (1.0f - z)*cd;
      h2own[uc][ur] = hn;
      short hb = f2bf(hn), lb = f2bf(hn - bf2f(hb));
      st_msg(&h2s[ur*512 + (rz + uc)*2], hb, lb, (unsigned)(t+1));
    }
    // h2(t) gather deferred to next step's A-window (epoch validates)

    // ---- B-window: L1(t+1) ----
    if (t + 1 < NT){
      f32x4 a1n = {0.f,0.f,0.f,0.f};
#pragma unroll
      for (int ks = 0; ks < 12; ++ks){
        bf16x8 bfr = *(bf16x8*)((char*)in1 + ln*768 + ((ks*64 + lk*16) ^ ((ln&7)<<4)));
        a1n = __builtin_amdgcn_mfma_f32_16x16x32_bf16(w1f[ks], bfr, a1n, 0, 0, 0);
      }
      acc1 = a1n;
    }
  }

  // ---- epilogue: gather h2(NT-1) (epoch NT), head(NT-1) ----
  if (sb < GR){
    if (tid < 128){
      unsigned* h2e = h2buf + (unsigned)((NT-1) & 1)*131072u + (unsigned)(gp*GR)*512u;
      bf16x8 hv, lv;
      gather8(&h2e[ur*512 + uc*16], (unsigned)NT, hv, lv);
      *(bf16x8*)((char*)in2 + ur*1024     + ((512 + uc*16) ^ ((ur&7)<<4))) = hv;
      *(bf16x8*)((char*)in2 + (ur+8)*1024 + ((512 + uc*16) ^ ((ur&7)<<4))) = lv;
    }
    __syncthreads();
    f32x4 acc3a = {0,0,0,0}, acc3b = {0,0,0,0};
#pragma unroll
    for (int ks = 0; ks < 8; ++ks){
      bf16x8 bfr = *(bf16x8*)((char*)in2 + ln*1024 + ((512 + ks*64 + lk*16) ^ ((ln&7)<<4)));
      acc3a = __builtin_amdgcn_mfma_f32_16x16x32_bf16(w3f[0][ks], bfr, acc3a, 0, 0, 0);
      acc3b = __builtin_amdgcn_mfma_f32_16x16x32_bf16(w3f[1][ks], bfr, acc3b, 0, 0, 0);
    }
    if (ln == sb){
#pragma unroll
      for (int r4 = 0; r4 < 4; ++r4){
        int d0 = wv*32 + lk*4 + r4;
        h3p[d0] = acc3a[r4]; h3p[d0+16] = acc3b[r4];
      }
    }
    if (ln == sb + 8){
#pragma unroll
      for (int r4 = 0; r4 < 4; ++r4){
        int d0 = wv*32 + lk*4 + r4;
        h3q[d0] = acc3a[r4]; h3q[d0+16] = acc3b[r4];
      }
    }
    __syncthreads();
    if (tid < 128) h3row[tid] = fmaxf(h3p[tid] + h3q[tid] + b3L[tid], 0.0f);
    __syncthreads();
    if (wv == 0){
      const int l = tid, c = l >> 2, kq = l & 3;
      float p = 0.f;
      if (c < 10){
        const float* wr = &W4L[c*130 + kq*32];
        const float* hr = &h3row[kq*32];
#pragma unroll
        for (int k = 0; k < 32; ++k) p += wr[k]*hr[k];
      }
      p += __shfl_xor(p, 1, 4);
      p += __shfl_xor(p, 2, 4);
      if (c < 10 && kq == 0) ytmp[c] = p + b4L[c];
      asm volatile("s_waitcnt lgkmcnt(0)" ::: "memory");
      float yv = (l < 10) ? ytmp[l] : -INFINITY;
      float mx = yv;
#pragma unroll
      for (int off = 1; off < 16; off <<= 1)
        mx = fmaxf(mx, __shfl_xor(mx, off, 16));
      float ex = (l < 10) ? expf(yv - mx) : 0.0f;
      float sm = ex;
#pragma unroll
      for (int off = 1; off < 16; off <<= 1)
        sm += __shfl_xor(sm, off, 16);
      if (l < 10)
        outg[((size_t)(gp*GR + sb)*NT + (NT-1))*NC + l] = yv - (mx + logf(sm));
    }
  }
}

extern "C" void kernel_launch(void* const* d_in, const int* in_sizes, int n_in,
                              void* d_out, int out_size, void* d_ws, size_t ws_size,
                              hipStream_t stream) {
  const float* xg  = (const float*)d_in[0];
  const float* h1i = (const float*)d_in[1];
  const float* h2i = (const float*)d_in[2];
  const float* W1  = (const float*)d_in[3];
  const float* b1  = (const float*)d_in[4];
  const float* W2  = (const float*)d_in[5];
  const float* b2  = (const float*)d_in[6];
  const float* W3  = (const float*)d_in[7];
  const float* b3  = (const float*)d_in[8];
  const float* W4  = (const float*)d_in[9];
  const float* b4  = (const float*)d_in[10];
  float* out = (float*)d_out;
  float* ws  = (float*)d_ws;

  // clear all message epochs (stale epochs from a previous replay would
  // falsely validate): h1buf 1 MiB + h2buf 1 MiB
  hipMemsetAsync(d_ws, 0, 2u * 1024u * 1024u, stream);

  egru_persistent<<<dim3(512), dim3(256), 0, stream>>>(
      xg, h1i, h2i, W1, b1, W2, b2, W3, b3, W4, b4, out, ws);
}

// Round 11
// 1807.789 us; speedup vs baseline: 1.9075x; 1.9075x over previous
//
#include <hip/hip_runtime.h>

#define NT 512   // timesteps
#define FB 128   // feature bins
#define HD 256   // L1 == L2 hidden
#define NC 10
#define NG 32    // groups
#define GR 8     // batch rows per group

typedef __attribute__((ext_vector_type(8))) short bf16x8;
typedef __attribute__((ext_vector_type(4))) float f32x4;
typedef __attribute__((ext_vector_type(4))) unsigned u32x4;

static __device__ __forceinline__ short f2bf(float f){
  union { float f; unsigned u; } v; v.f = f;
  return (short)((v.u + 0x7fffu + ((v.u >> 16) & 1u)) >> 16);  // RNE
}
static __device__ __forceinline__ float bf2f(short h){
  union { unsigned u; float f; } v; v.u = ((unsigned)(unsigned short)h) << 16;
  return v.f;
}
static __device__ __forceinline__ float quantw(float w){
  return fminf(fmaxf(rintf(w * 8.0f) * 0.125f, -1.0f), 1.0f);  // exact in bf16
}
static __device__ __forceinline__ bf16x8 loadqw8(const float* __restrict__ p){
  bf16x8 v;
#pragma unroll
  for (int j = 0; j < 8; ++j) v[j] = f2bf(quantw(p[j]));
  return v;
}
static __device__ __forceinline__ void split8(f32x4 a, f32x4 b, bf16x8& hi, bf16x8& lo){
  float v0[4] = {a[0],a[1],a[2],a[3]}, v1[4] = {b[0],b[1],b[2],b[3]};
#pragma unroll
  for (int j = 0; j < 4; ++j){
    short h = f2bf(v0[j]); hi[j] = h; lo[j] = f2bf(v0[j] - bf2f(h));
  }
#pragma unroll
  for (int j = 0; j < 4; ++j){
    short h = f2bf(v1[j]); hi[4+j] = h; lo[4+j] = f2bf(v1[j] - bf2f(h));
  }
}

// ---- epoch-in-band messaging over sc1 (R9-proven mechanism) ----
static __device__ __forceinline__ void st_msg(unsigned* p, short hb, short lb, unsigned ep){
  __attribute__((ext_vector_type(2))) unsigned w;
  w[0] = (((unsigned)(unsigned short)hb) << 16) | ep;
  w[1] = (((unsigned)(unsigned short)lb) << 16) | ep;
  asm volatile("global_store_dwordx2 %0, %1, off sc1" :: "v"(p), "v"(w) : "memory");
}
// blocking gather with retry (fallback path; drains vmcnt(0))
static __device__ __forceinline__ void gather8(const unsigned* p, unsigned ep, bf16x8& hv, bf16x8& lv){
  u32x4 a, b, c, d;
  for (;;){
    asm volatile("global_load_dwordx4 %0, %4, off sc1\n\t"
                 "global_load_dwordx4 %1, %4, off offset:16 sc1\n\t"
                 "global_load_dwordx4 %2, %4, off offset:32 sc1\n\t"
                 "global_load_dwordx4 %3, %4, off offset:48 sc1\n\t"
                 "s_waitcnt vmcnt(0)"
                 : "=&v"(a), "=&v"(b), "=&v"(c), "=&v"(d) : "v"(p) : "memory");
    unsigned m = (a[0]^ep)|(a[1]^ep)|(a[2]^ep)|(a[3]^ep)
               | (b[0]^ep)|(b[1]^ep)|(b[2]^ep)|(b[3]^ep)
               | (c[0]^ep)|(c[1]^ep)|(c[2]^ep)|(c[3]^ep)
               | (d[0]^ep)|(d[1]^ep)|(d[2]^ep)|(d[3]^ep);
    if ((m & 0xffffu) == 0u) break;
  }
  hv[0]=(short)(a[0]>>16); lv[0]=(short)(a[1]>>16);
  hv[1]=(short)(a[2]>>16); lv[1]=(short)(a[3]>>16);
  hv[2]=(short)(b[0]>>16); lv[2]=(short)(b[1]>>16);
  hv[3]=(short)(b[2]>>16); lv[3]=(short)(b[3]>>16);
  hv[4]=(short)(c[0]>>16); lv[4]=(short)(c[1]>>16);
  hv[5]=(short)(c[2]>>16); lv[5]=(short)(c[3]>>16);
  hv[6]=(short)(d[0]>>16); lv[6]=(short)(d[1]>>16);
  hv[7]=(short)(d[2]>>16); lv[7]=(short)(d[3]>>16);
}
static __device__ __forceinline__ bool chk_unpack(u32x4 a, u32x4 b, u32x4 c, u32x4 d,
                                                  unsigned ep, bf16x8& hv, bf16x8& lv){
  unsigned m = (a[0]^ep)|(a[1]^ep)|(a[2]^ep)|(a[3]^ep)
             | (b[0]^ep)|(b[1]^ep)|(b[2]^ep)|(b[3]^ep)
             | (c[0]^ep)|(c[1]^ep)|(c[2]^ep)|(c[3]^ep)
             | (d[0]^ep)|(d[1]^ep)|(d[2]^ep)|(d[3]^ep);
  if ((m & 0xffffu) != 0u) return false;
  hv[0]=(short)(a[0]>>16); lv[0]=(short)(a[1]>>16);
  hv[1]=(short)(a[2]>>16); lv[1]=(short)(a[3]>>16);
  hv[2]=(short)(b[0]>>16); lv[2]=(short)(b[1]>>16);
  hv[3]=(short)(b[2]>>16); lv[3]=(short)(b[3]>>16);
  hv[4]=(short)(c[0]>>16); lv[4]=(short)(c[1]>>16);
  hv[5]=(short)(c[2]>>16); lv[5]=(short)(c[3]>>16);
  hv[6]=(short)(d[0]>>16); lv[6]=(short)(d[1]>>16);
  hv[7]=(short)(d[2]>>16); lv[7]=(short)(d[3]>>16);
  return true;
}

// issue-only loads (no waitcnt) — T14 split
#define ISSUE_G8(P,A,B,C,D) \
  asm volatile("global_load_dwordx4 %0, %4, off sc1\n\t" \
               "global_load_dwordx4 %1, %4, off offset:16 sc1\n\t" \
               "global_load_dwordx4 %2, %4, off offset:32 sc1\n\t" \
               "global_load_dwordx4 %3, %4, off offset:48 sc1" \
               : "=&v"(A),"=&v"(B),"=&v"(C),"=&v"(D) : "v"(P) : "memory")
#define ISSUE_X2(P,A,B) \
  asm volatile("global_load_dwordx4 %0, %2, off\n\t" \
               "global_load_dwordx4 %1, %2, off offset:16" \
               : "=&v"(A),"=&v"(B) : "v"(P) : "memory")
// counted waits; "+v" rebinds force def-use ordering; sched_barrier per rule #18
#define WAITV4(N,A,B,C,D) do{ \
  asm volatile("s_waitcnt vmcnt(" #N ")" : "+v"(A),"+v"(B),"+v"(C),"+v"(D) :: "memory"); \
  __builtin_amdgcn_sched_barrier(0); }while(0)
#define WAITV2(N,A,B) do{ \
  asm volatile("s_waitcnt vmcnt(" #N ")" : "+v"(A),"+v"(B) :: "memory"); \
  __builtin_amdgcn_sched_barrier(0); }while(0)
// raw barrier: LDS ordering WITHOUT vmcnt drain (no sc1 store-ack stalls)
#define BARRIER() do{ asm volatile("s_waitcnt lgkmcnt(0)" ::: "memory"); \
  __builtin_amdgcn_s_barrier(); asm volatile("" ::: "memory"); }while(0)

// 256 blocks x 256 threads, 1 block/CU. gp = bid&31, sb = bid>>5 (same-XCD peers).
// Single-MFMA hi|lo; epoch messaging; deferred h2 gather; split-issue gathers with
// counted vmcnt; raw barriers; fragments read ONCE and reused (h1: L2+L1; h2: L2+head).
__global__ __launch_bounds__(256, 1)
void egru_persistent(const float* __restrict__ xg,
                     const float* __restrict__ h1ig, const float* __restrict__ h2ig,
                     const float* __restrict__ W1g, const float* __restrict__ b1g,
                     const float* __restrict__ W2g, const float* __restrict__ b2g,
                     const float* __restrict__ W3g, const float* __restrict__ b3g,
                     const float* __restrict__ W4g, const float* __restrict__ b4g,
                     float* __restrict__ outg, float* __restrict__ wsf)
{
  const int tid = threadIdx.x;
  const int gp  = blockIdx.x & 31;
  const int sb  = blockIdx.x >> 5;
  const int wv  = tid >> 6;
  const int ln  = tid & 15;
  const int lk  = (tid >> 4) & 3;
  const int rz  = sb * 32;

  __shared__ __align__(16) short inX [16*128];  // x(t); rows 0-7 hi, 8-15 lo; 256 B/row
  __shared__ __align__(16) short inH1[16*256];  // h1(t); 512 B/row
  __shared__ __align__(16) short inH2[16*256];  // h2(t-1); 512 B/row
  __shared__ float aldsA[64][17];
  __shared__ float aldsB[64][17];
  __shared__ float h1own[32][GR];
  __shared__ float h2own[32][GR];
  __shared__ float h3p[128], h3q[128], h3row[128];
  __shared__ float ytmp[16];
  __shared__ float W4L[1344];                   // skewed: idx = c*134 + (k>>5)*33 + (k&31)
  __shared__ float b1s[64], b2s[64], b3L[128], b4L[10];

  unsigned* h1buf = reinterpret_cast<unsigned*>(wsf);
  unsigned* h2buf = h1buf + 262144;

  bf16x8 w1f[12], w2f[16], w3f[2][8];
  {
    const int arow = (wv < 2) ? (rz + wv*16 + ln) : (256 + rz + (wv-2)*16 + ln);
#pragma unroll
    for (int ks = 0; ks < 12; ++ks) w1f[ks] = loadqw8(W1g + arow*384 + ks*32 + lk*8);
#pragma unroll
    for (int ks = 0; ks < 16; ++ks) w2f[ks] = loadqw8(W2g + arow*512 + ks*32 + lk*8);
#pragma unroll
    for (int tl = 0; tl < 2; ++tl)
#pragma unroll
      for (int ks = 0; ks < 8; ++ks)
        w3f[tl][ks] = loadqw8(W3g + (wv*32 + tl*16 + ln)*256 + ks*32 + lk*8);
  }

  if (tid < 64){
    int grow = (tid < 32) ? (rz + tid) : (256 + rz + (tid - 32));
    b1s[tid] = b1g[grow];
    b2s[tid] = b2g[grow];
  }
  if (tid < 128) b3L[tid] = b3g[tid];
  if (tid < 10)  b4L[tid] = b4g[tid];
  for (int i = tid; i < 1280; i += 256){
    int c = i >> 7, k = i & 127;
    W4L[c*134 + (k>>5)*33 + (k&31)] = quantw(W4g[i]);
  }

  const int ur = tid >> 5, uc = tid & 31;   // (batch row, dim/chunk) mapping, 8x32
  {
    bf16x8 hv, lv;
    const float* p1 = h1ig + (size_t)(gp*GR + ur)*HD + uc*8;
    split8(*(const f32x4*)p1, *(const f32x4*)(p1+4), hv, lv);
    *(bf16x8*)((char*)inH1 + ur*512     + ((uc*16) ^ ((ur&7)<<4))) = hv;
    *(bf16x8*)((char*)inH1 + (ur+8)*512 + ((uc*16) ^ ((ur&7)<<4))) = lv;
    const float* p2 = h2ig + (size_t)(gp*GR + ur)*HD + uc*8;
    split8(*(const f32x4*)p2, *(const f32x4*)(p2+4), hv, lv);
    *(bf16x8*)((char*)inH2 + ur*512     + ((uc*16) ^ ((ur&7)<<4))) = hv;
    *(bf16x8*)((char*)inH2 + (ur+8)*512 + ((uc*16) ^ ((ur&7)<<4))) = lv;
    h1own[uc][ur] = h1ig[(size_t)(gp*GR+ur)*HD + rz + uc];
    h2own[uc][ur] = h2ig[(size_t)(gp*GR+ur)*HD + rz + uc];
  }
  const int xr = tid >> 4, xf = tid & 15;
  if (xr < 8){
    const float* px = xg + ((size_t)(gp*GR + xr)*NT + 0)*FB + xf*8;
    bf16x8 hv, lv;
    split8(*(const f32x4*)px, *(const f32x4*)(px+4), hv, lv);
    *(bf16x8*)((char*)inX + xr*256     + ((xf*16) ^ ((xr&7)<<4))) = hv;
    *(bf16x8*)((char*)inX + (xr+8)*256 + ((xf*16) ^ ((xr&7)<<4))) = lv;
  }
  __syncthreads();   // full drain at init boundary (intentional)

  // ---- prologue: acc1 = L1(0) = W1·[x(0); h1(0)] ----
  f32x4 acc1 = {0.f,0.f,0.f,0.f};
#pragma unroll
  for (int j = 0; j < 4; ++j){
    bf16x8 fx = *(bf16x8*)((char*)inX + ln*256 + ((j*64 + lk*16) ^ ((ln&7)<<4)));
    acc1 = __builtin_amdgcn_mfma_f32_16x16x32_bf16(w1f[j], fx, acc1, 0, 0, 0);
  }
#pragma unroll
  for (int j = 0; j < 8; ++j){
    bf16x8 fh = *(bf16x8*)((char*)inH1 + ln*512 + ((j*64 + lk*16) ^ ((ln&7)<<4)));
    acc1 = __builtin_amdgcn_mfma_f32_16x16x32_bf16(w1f[4+j], fh, acc1, 0, 0, 0);
  }

  for (int t = 0; t < NT; ++t){
    unsigned* h1s = h1buf + (unsigned)(t & 1)*131072u + (unsigned)(gp*GR)*512u;
    unsigned* h2s = h2buf + (unsigned)(t & 1)*131072u + (unsigned)(gp*GR)*512u;
    unsigned* h2r = h2buf + (unsigned)((t + 1) & 1)*131072u + (unsigned)(gp*GR)*512u;

    // issue h2(t-1) gather loads (epoch t) — consumed after A1
    u32x4 g2a, g2b, g2c, g2d;
    if (t > 0) ISSUE_G8(&h2r[ur*512 + uc*16], g2a, g2b, g2c, g2d);

    // ---- A1: finish h1(t) ----
#pragma unroll
    for (int r4 = 0; r4 < 4; ++r4)
      aldsA[wv*16 + lk*4 + r4][ln] = acc1[r4];   // C/D: row=(lane>>4)*4+reg, col=lane&15
    BARRIER();
    {
      float az = aldsA[uc][ur]    + aldsA[uc][ur+8]    + b1s[uc];
      float ac = aldsA[32+uc][ur] + aldsA[32+uc][ur+8] + b1s[32+uc];
      float z  = 0.5f*(az/(1.0f+fabsf(az)) + 1.0f);
      float cd = ac/(1.0f+fabsf(ac));
      float hn = z*h1own[uc][ur] + (1.0f - z)*cd;
      h1own[uc][ur] = hn;
      short hb = f2bf(hn), lb = f2bf(hn - bf2f(hb));
      st_msg(&h1s[ur*512 + (rz + uc)*2], hb, lb, (unsigned)(t+1));
    }

    // consume h2(t-1): outstanding [stH2(t-1)?, g2 x4, stH1] -> vmcnt(1) completes g2, leaves stH1
    if (t > 0){
      WAITV4(1, g2a, g2b, g2c, g2d);
      bf16x8 hv, lv;
      if (!chk_unpack(g2a, g2b, g2c, g2d, (unsigned)t, hv, lv))
        gather8(&h2r[ur*512 + uc*16], (unsigned)t, hv, lv);
      *(bf16x8*)((char*)inH2 + ur*512     + ((uc*16) ^ ((ur&7)<<4))) = hv;
      *(bf16x8*)((char*)inH2 + (ur+8)*512 + ((uc*16) ^ ((ur&7)<<4))) = lv;
    }

    // issue h1(t) gather (optimistic) + x(t+1) loads
    u32x4 g1a, g1b, g1c, g1d;
    ISSUE_G8(&h1s[ur*512 + uc*16], g1a, g1b, g1c, g1d);
    f32x4 xa = {0,0,0,0}, xb = {0,0,0,0};
    const bool pf = ((t+1) < NT) && (xr < 8);
    if (pf){
      const float* px = xg + ((size_t)(gp*GR + xr)*NT + (t+1))*FB + xf*8;
      ISSUE_X2(px, xa, xb);
    }
    BARRIER();   // inH2 visible

    // ---- A-window: fh2 frags once -> L2-h2half + head(t-1) ----
    bf16x8 fh2[8];
#pragma unroll
    for (int j = 0; j < 8; ++j)
      fh2[j] = *(bf16x8*)((char*)inH2 + ln*512 + ((j*64 + lk*16) ^ ((ln&7)<<4)));
    f32x4 acc2 = {0.f,0.f,0.f,0.f};
#pragma unroll
    for (int j = 0; j < 8; ++j)
      acc2 = __builtin_amdgcn_mfma_f32_16x16x32_bf16(w2f[8+j], fh2[j], acc2, 0, 0, 0);

    float outv = 0.f; bool dow = false; size_t oaddr = 0;
    if (t > 0){
      f32x4 acc3a = {0,0,0,0}, acc3b = {0,0,0,0};
#pragma unroll
      for (int j = 0; j < 8; ++j){
        acc3a = __builtin_amdgcn_mfma_f32_16x16x32_bf16(w3f[0][j], fh2[j], acc3a, 0, 0, 0);
        acc3b = __builtin_amdgcn_mfma_f32_16x16x32_bf16(w3f[1][j], fh2[j], acc3b, 0, 0, 0);
      }
      if (ln == sb){
#pragma unroll
        for (int r4 = 0; r4 < 4; ++r4){
          int d0 = wv*32 + lk*4 + r4;
          h3p[d0] = acc3a[r4]; h3p[d0+16] = acc3b[r4];
        }
      }
      if (ln == sb + 8){
#pragma unroll
        for (int r4 = 0; r4 < 4; ++r4){
          int d0 = wv*32 + lk*4 + r4;
          h3q[d0] = acc3a[r4]; h3q[d0+16] = acc3b[r4];
        }
      }
      BARRIER();
      if (tid < 128) h3row[tid] = fmaxf(h3p[tid] + h3q[tid] + b3L[tid], 0.0f);
      BARRIER();
      if (wv == 0){
        const int l = tid, c = l >> 2, kq = l & 3;
        float p = 0.f;
        if (c < 10){
          const float* wr = &W4L[c*134 + kq*33];
          const float* hr = &h3row[kq*32];
#pragma unroll
          for (int k = 0; k < 32; ++k) p += wr[k]*hr[k];
        }
        p += __shfl_xor(p, 1, 4);
        p += __shfl_xor(p, 2, 4);
        if (c < 10 && kq == 0) ytmp[c] = p + b4L[c];
        asm volatile("s_waitcnt lgkmcnt(0)" ::: "memory");
        float yv = (l < 10) ? ytmp[l] : -INFINITY;
        float mx = yv;
#pragma unroll
        for (int off = 1; off < 16; off <<= 1)
          mx = fmaxf(mx, __shfl_xor(mx, off, 16));
        float ex = (l < 10) ? expf(yv - mx) : 0.0f;
        float sm = ex;
#pragma unroll
        for (int off = 1; off < 16; off <<= 1)
          sm += __shfl_xor(sm, off, 16);
        if (l < 10){
          outv = yv - (mx + logf(sm));
          dow = true;
          oaddr = ((size_t)(gp*GR + sb)*NT + (t-1))*NC + l;
        }
      }
    }

    // consume h1(t): outstanding [stH1?, g1 x4, x x2] -> vmcnt(2) completes g1, leaves x
    {
      WAITV4(2, g1a, g1b, g1c, g1d);
      bf16x8 hv, lv;
      if (!chk_unpack(g1a, g1b, g1c, g1d, (unsigned)(t+1), hv, lv))
        gather8(&h1s[ur*512 + uc*16], (unsigned)(t+1), hv, lv);
      *(bf16x8*)((char*)inH1 + ur*512     + ((uc*16) ^ ((ur&7)<<4))) = hv;
      *(bf16x8*)((char*)inH1 + (ur+8)*512 + ((uc*16) ^ ((ur&7)<<4))) = lv;
    }
    if (dow) outg[oaddr] = outv;   // deferred so vmcnt counts stay wave-uniform
    BARRIER();   // inH1 visible

    // ---- B: fh1 frags once -> L2-h1half; gate h2 ----
    bf16x8 fh1[8];
#pragma unroll
    for (int j = 0; j < 8; ++j)
      fh1[j] = *(bf16x8*)((char*)inH1 + ln*512 + ((j*64 + lk*16) ^ ((ln&7)<<4)));
#pragma unroll
    for (int j = 0; j < 8; ++j)
      acc2 = __builtin_amdgcn_mfma_f32_16x16x32_bf16(w2f[j], fh1[j], acc2, 0, 0, 0);
#pragma unroll
    for (int r4 = 0; r4 < 4; ++r4)
      aldsB[wv*16 + lk*4 + r4][ln] = acc2[r4];
    BARRIER();
    {
      float az = aldsB[uc][ur]    + aldsB[uc][ur+8]    + b2s[uc];
      float ac = aldsB[32+uc][ur] + aldsB[32+uc][ur+8] + b2s[32+uc];
      float z  = 0.5f*(az/(1.0f+fabsf(az)) + 1.0f);
      float cd = ac/(1.0f+fabsf(ac));
      float hn = z*h2own[uc][ur] + (1.0f - z)*cd;
      h2own[uc][ur] = hn;
      short hb = f2bf(hn), lb = f2bf(hn - bf2f(hb));
      st_msg(&h2s[ur*512 + (rz + uc)*2], hb, lb, (unsigned)(t+1));
    }

    // consume x(t+1): outstanding [x x2, outg?, stH2] -> vmcnt(1) completes x (+outg on wave0)
    WAITV2(1, xa, xb);
    if (pf){
      bf16x8 hv, lv;
      split8(xa, xb, hv, lv);
      *(bf16x8*)((char*)inX + xr*256     + ((xf*16) ^ ((xr&7)<<4))) = hv;
      *(bf16x8*)((char*)inX + (xr+8)*256 + ((xf*16) ^ ((xr&7)<<4))) = lv;
    }
    BARRIER();   // inX visible

    // ---- B-window: L1(t+1) = x-part (LDS) + h1-part (fh1 regs, reused) ----
    if (t + 1 < NT){
      f32x4 a1n = {0.f,0.f,0.f,0.f};
#pragma unroll
      for (int j = 0; j < 4; ++j){
        bf16x8 fx = *(bf16x8*)((char*)inX + ln*256 + ((j*64 + lk*16) ^ ((ln&7)<<4)));
        a1n = __builtin_amdgcn_mfma_f32_16x16x32_bf16(w1f[j], fx, a1n, 0, 0, 0);
      }
#pragma unroll
      for (int j = 0; j < 8; ++j)
        a1n = __builtin_amdgcn_mfma_f32_16x16x32_bf16(w1f[4+j], fh1[j], a1n, 0, 0, 0);
      acc1 = a1n;
    }
  }

  // ---- epilogue: gather h2(NT-1) (epoch NT), head(NT-1) ----
  {
    unsigned* h2e = h2buf + (unsigned)((NT-1) & 1)*131072u + (unsigned)(gp*GR)*512u;
    bf16x8 hv, lv;
    gather8(&h2e[ur*512 + uc*16], (unsigned)NT, hv, lv);
    *(bf16x8*)((char*)inH2 + ur*512     + ((uc*16) ^ ((ur&7)<<4))) = hv;
    *(bf16x8*)((char*)inH2 + (ur+8)*512 + ((uc*16) ^ ((ur&7)<<4))) = lv;
  }
  BARRIER();
  {
    bf16x8 fh2[8];
#pragma unroll
    for (int j = 0; j < 8; ++j)
      fh2[j] = *(bf16x8*)((char*)inH2 + ln*512 + ((j*64 + lk*16) ^ ((ln&7)<<4)));
    f32x4 acc3a = {0,0,0,0}, acc3b = {0,0,0,0};
#pragma unroll
    for (int j = 0; j < 8; ++j){
      acc3a = __builtin_amdgcn_mfma_f32_16x16x32_bf16(w3f[0][j], fh2[j], acc3a, 0, 0, 0);
      acc3b = __builtin_amdgcn_mfma_f32_16x16x32_bf16(w3f[1][j], fh2[j], acc3b, 0, 0, 0);
    }
    if (ln == sb){
#pragma unroll
      for (int r4 = 0; r4 < 4; ++r4){
        int d0 = wv*32 + lk*4 + r4;
        h3p[d0] = acc3a[r4]; h3p[d0+16] = acc3b[r4];
      }
    }
    if (ln == sb + 8){
#pragma unroll
      for (int r4 = 0; r4 < 4; ++r4){
        int d0 = wv*32 + lk*4 + r4;
        h3q[d0] = acc3a[r4]; h3q[d0+16] = acc3b[r4];
      }
    }
    BARRIER();
    if (tid < 128) h3row[tid] = fmaxf(h3p[tid] + h3q[tid] + b3L[tid], 0.0f);
    BARRIER();
    if (wv == 0){
      const int l = tid, c = l >> 2, kq = l & 3;
      float p = 0.f;
      if (c < 10){
        const float* wr = &W4L[c*134 + kq*33];
        const float* hr = &h3row[kq*32];
#pragma unroll
        for (int k = 0; k < 32; ++k) p += wr[k]*hr[k];
      }
      p += __shfl_xor(p, 1, 4);
      p += __shfl_xor(p, 2, 4);
      if (c < 10 && kq == 0) ytmp[c] = p + b4L[c];
      asm volatile("s_waitcnt lgkmcnt(0)" ::: "memory");
      float yv = (l < 10) ? ytmp[l] : -INFINITY;
      float mx = yv;
#pragma unroll
      for (int off = 1; off < 16; off <<= 1)
        mx = fmaxf(mx, __shfl_xor(mx, off, 16));
      float ex = (l < 10) ? expf(yv - mx) : 0.0f;
      float sm = ex;
#pragma unroll
      for (int off = 1; off < 16; off <<= 1)
        sm += __shfl_xor(sm, off, 16);
      if (l < 10)
        outg[((size_t)(gp*GR + sb)*NT + (NT-1))*NC + l] = yv - (mx + logf(sm));
    }
  }
}

extern "C" void kernel_launch(void* const* d_in, const int* in_sizes, int n_in,
                              void* d_out, int out_size, void* d_ws, size_t ws_size,
                              hipStream_t stream) {
  const float* xg  = (const float*)d_in[0];
  const float* h1i = (const float*)d_in[1];
  const float* h2i = (const float*)d_in[2];
  const float* W1  = (const float*)d_in[3];
  const float* b1  = (const float*)d_in[4];
  const float* W2  = (const float*)d_in[5];
  const float* b2  = (const float*)d_in[6];
  const float* W3  = (const float*)d_in[7];
  const float* b3  = (const float*)d_in[8];
  const float* W4  = (const float*)d_in[9];
  const float* b4  = (const float*)d_in[10];
  float* out = (float*)d_out;
  float* ws  = (float*)d_ws;

  // clear all message epochs (stale epochs from a previous replay would falsely validate)
  hipMemsetAsync(d_ws, 0, 2u * 1024u * 1024u, stream);

  egru_persistent<<<dim3(256), dim3(256), 0, stream>>>(
      xg, h1i, h2i, W1, b1, W2, b2, W3, b3, W4, b4, out, ws);
}

// Round 12
// 1759.612 us; speedup vs baseline: 1.9597x; 1.0274x over previous
//
#include <hip/hip_runtime.h>

#define NT 512   // timesteps
#define FB 128   // feature bins
#define HD 256   // L1 == L2 hidden
#define NC 10
#define NG 32    // groups
#define GR 8     // batch rows per group

typedef __attribute__((ext_vector_type(8))) short bf16x8;
typedef __attribute__((ext_vector_type(4))) float f32x4;
typedef __attribute__((ext_vector_type(4))) unsigned u32x4;

static __device__ __forceinline__ short f2bf(float f){
  union { float f; unsigned u; } v; v.f = f;
  return (short)((v.u + 0x7fffu + ((v.u >> 16) & 1u)) >> 16);  // RNE
}
static __device__ __forceinline__ float bf2f(short h){
  union { unsigned u; float f; } v; v.u = ((unsigned)(unsigned short)h) << 16;
  return v.f;
}
static __device__ __forceinline__ float quantw(float w){
  return fminf(fmaxf(rintf(w * 8.0f) * 0.125f, -1.0f), 1.0f);  // exact in bf16
}
static __device__ __forceinline__ bf16x8 loadqw8(const float* __restrict__ p){
  bf16x8 v;
#pragma unroll
  for (int j = 0; j < 8; ++j) v[j] = f2bf(quantw(p[j]));
  return v;
}
static __device__ __forceinline__ void split8(f32x4 a, f32x4 b, bf16x8& hi, bf16x8& lo){
  float v0[4] = {a[0],a[1],a[2],a[3]}, v1[4] = {b[0],b[1],b[2],b[3]};
#pragma unroll
  for (int j = 0; j < 4; ++j){
    short h = f2bf(v0[j]); hi[j] = h; lo[j] = f2bf(v0[j] - bf2f(h));
  }
#pragma unroll
  for (int j = 0; j < 4; ++j){
    short h = f2bf(v1[j]); hi[4+j] = h; lo[4+j] = f2bf(v1[j] - bf2f(h));
  }
}

// ---- epoch-in-band messaging over sc1 (R9-proven mechanism) ----
static __device__ __forceinline__ void st_msg(unsigned* p, short hb, short lb, unsigned ep){
  __attribute__((ext_vector_type(2))) unsigned w;
  w[0] = (((unsigned)(unsigned short)hb) << 16) | ep;
  w[1] = (((unsigned)(unsigned short)lb) << 16) | ep;
  asm volatile("global_store_dwordx2 %0, %1, off sc1" :: "v"(p), "v"(w) : "memory");
}
// blocking gather with retry (fallback path; drains vmcnt(0))
static __device__ __forceinline__ void gather8(const unsigned* p, unsigned ep, bf16x8& hv, bf16x8& lv){
  u32x4 a, b, c, d;
  for (;;){
    asm volatile("global_load_dwordx4 %0, %4, off sc1\n\t"
                 "global_load_dwordx4 %1, %4, off offset:16 sc1\n\t"
                 "global_load_dwordx4 %2, %4, off offset:32 sc1\n\t"
                 "global_load_dwordx4 %3, %4, off offset:48 sc1\n\t"
                 "s_waitcnt vmcnt(0)"
                 : "=&v"(a), "=&v"(b), "=&v"(c), "=&v"(d) : "v"(p) : "memory");
    unsigned m = (a[0]^ep)|(a[1]^ep)|(a[2]^ep)|(a[3]^ep)
               | (b[0]^ep)|(b[1]^ep)|(b[2]^ep)|(b[3]^ep)
               | (c[0]^ep)|(c[1]^ep)|(c[2]^ep)|(c[3]^ep)
               | (d[0]^ep)|(d[1]^ep)|(d[2]^ep)|(d[3]^ep);
    if ((m & 0xffffu) == 0u) break;
  }
  hv[0]=(short)(a[0]>>16); lv[0]=(short)(a[1]>>16);
  hv[1]=(short)(a[2]>>16); lv[1]=(short)(a[3]>>16);
  hv[2]=(short)(b[0]>>16); lv[2]=(short)(b[1]>>16);
  hv[3]=(short)(b[2]>>16); lv[3]=(short)(b[3]>>16);
  hv[4]=(short)(c[0]>>16); lv[4]=(short)(c[1]>>16);
  hv[5]=(short)(c[2]>>16); lv[5]=(short)(c[3]>>16);
  hv[6]=(short)(d[0]>>16); lv[6]=(short)(d[1]>>16);
  hv[7]=(short)(d[2]>>16); lv[7]=(short)(d[3]>>16);
}
static __device__ __forceinline__ bool chk_unpack(u32x4 a, u32x4 b, u32x4 c, u32x4 d,
                                                  unsigned ep, bf16x8& hv, bf16x8& lv){
  unsigned m = (a[0]^ep)|(a[1]^ep)|(a[2]^ep)|(a[3]^ep)
             | (b[0]^ep)|(b[1]^ep)|(b[2]^ep)|(b[3]^ep)
             | (c[0]^ep)|(c[1]^ep)|(c[2]^ep)|(c[3]^ep)
             | (d[0]^ep)|(d[1]^ep)|(d[2]^ep)|(d[3]^ep);
  if ((m & 0xffffu) != 0u) return false;
  hv[0]=(short)(a[0]>>16); lv[0]=(short)(a[1]>>16);
  hv[1]=(short)(a[2]>>16); lv[1]=(short)(a[3]>>16);
  hv[2]=(short)(b[0]>>16); lv[2]=(short)(b[1]>>16);
  hv[3]=(short)(b[2]>>16); lv[3]=(short)(b[3]>>16);
  hv[4]=(short)(c[0]>>16); lv[4]=(short)(c[1]>>16);
  hv[5]=(short)(c[2]>>16); lv[5]=(short)(c[3]>>16);
  hv[6]=(short)(d[0]>>16); lv[6]=(short)(d[1]>>16);
  hv[7]=(short)(d[2]>>16); lv[7]=(short)(d[3]>>16);
  return true;
}

// issue-only loads (no waitcnt) — T14 split
#define ISSUE_G8(P,A,B,C,D) \
  asm volatile("global_load_dwordx4 %0, %4, off sc1\n\t" \
               "global_load_dwordx4 %1, %4, off offset:16 sc1\n\t" \
               "global_load_dwordx4 %2, %4, off offset:32 sc1\n\t" \
               "global_load_dwordx4 %3, %4, off offset:48 sc1" \
               : "=&v"(A),"=&v"(B),"=&v"(C),"=&v"(D) : "v"(P) : "memory")
#define ISSUE_X2(P,A,B) \
  asm volatile("global_load_dwordx4 %0, %2, off\n\t" \
               "global_load_dwordx4 %1, %2, off offset:16" \
               : "=&v"(A),"=&v"(B) : "v"(P) : "memory")
// counted waits; "+v" rebinds force def-use ordering; sched_barrier per rule #18
#define WAITV4(N,A,B,C,D) do{ \
  asm volatile("s_waitcnt vmcnt(" #N ")" : "+v"(A),"+v"(B),"+v"(C),"+v"(D) :: "memory"); \
  __builtin_amdgcn_sched_barrier(0); }while(0)
#define WAITV2(N,A,B) do{ \
  asm volatile("s_waitcnt vmcnt(" #N ")" : "+v"(A),"+v"(B) :: "memory"); \
  __builtin_amdgcn_sched_barrier(0); }while(0)
// raw barrier: LDS ordering WITHOUT vmcnt drain (no sc1 store-ack stalls)
#define BARRIER() do{ asm volatile("s_waitcnt lgkmcnt(0)" ::: "memory"); \
  __builtin_amdgcn_s_barrier(); asm volatile("" ::: "memory"); }while(0)

// 256 blocks x 256 threads, 1 block/CU. gp = bid&31, sb = bid>>5 (same-XCD peers).
// Single-MFMA hi|lo; epoch messaging; deferred h2 gather; split-issue gathers with
// WAVE-UNIFORM counted vmcnt (x-loads issued by ALL threads); h1 gather issued
// late (after L2-h2half) so it samples the coherent point after peer stores land.
__global__ __launch_bounds__(256, 1)
void egru_persistent(const float* __restrict__ xg,
                     const float* __restrict__ h1ig, const float* __restrict__ h2ig,
                     const float* __restrict__ W1g, const float* __restrict__ b1g,
                     const float* __restrict__ W2g, const float* __restrict__ b2g,
                     const float* __restrict__ W3g, const float* __restrict__ b3g,
                     const float* __restrict__ W4g, const float* __restrict__ b4g,
                     float* __restrict__ outg, float* __restrict__ wsf)
{
  const int tid = threadIdx.x;
  const int gp  = blockIdx.x & 31;
  const int sb  = blockIdx.x >> 5;
  const int wv  = tid >> 6;
  const int ln  = tid & 15;
  const int lk  = (tid >> 4) & 3;
  const int rz  = sb * 32;

  __shared__ __align__(16) short inX [16*128];  // x(t); rows 0-7 hi, 8-15 lo; 256 B/row
  __shared__ __align__(16) short inH1[16*256];  // h1(t); 512 B/row
  __shared__ __align__(16) short inH2[16*256];  // h2(t-1); 512 B/row
  __shared__ float aldsA[64][17];
  __shared__ float aldsB[64][17];
  __shared__ float h1own[32][GR];
  __shared__ float h2own[32][GR];
  __shared__ float h3p[128], h3q[128], h3row[128];
  __shared__ float ytmp[16];
  __shared__ float W4L[1344];                   // skewed: idx = c*134 + (k>>5)*33 + (k&31)
  __shared__ float b1s[64], b2s[64], b3L[128], b4L[10];

  unsigned* h1buf = reinterpret_cast<unsigned*>(wsf);
  unsigned* h2buf = h1buf + 262144;

  bf16x8 w1f[12], w2f[16], w3f[2][8];
  {
    const int arow = (wv < 2) ? (rz + wv*16 + ln) : (256 + rz + (wv-2)*16 + ln);
#pragma unroll
    for (int ks = 0; ks < 12; ++ks) w1f[ks] = loadqw8(W1g + arow*384 + ks*32 + lk*8);
#pragma unroll
    for (int ks = 0; ks < 16; ++ks) w2f[ks] = loadqw8(W2g + arow*512 + ks*32 + lk*8);
#pragma unroll
    for (int tl = 0; tl < 2; ++tl)
#pragma unroll
      for (int ks = 0; ks < 8; ++ks)
        w3f[tl][ks] = loadqw8(W3g + (wv*32 + tl*16 + ln)*256 + ks*32 + lk*8);
  }

  if (tid < 64){
    int grow = (tid < 32) ? (rz + tid) : (256 + rz + (tid - 32));
    b1s[tid] = b1g[grow];
    b2s[tid] = b2g[grow];
  }
  if (tid < 128) b3L[tid] = b3g[tid];
  if (tid < 10)  b4L[tid] = b4g[tid];
  for (int i = tid; i < 1280; i += 256){
    int c = i >> 7, k = i & 127;
    W4L[c*134 + (k>>5)*33 + (k&31)] = quantw(W4g[i]);
  }

  const int ur = tid >> 5, uc = tid & 31;   // (batch row, dim/chunk) mapping, 8x32
  {
    bf16x8 hv, lv;
    const float* p1 = h1ig + (size_t)(gp*GR + ur)*HD + uc*8;
    split8(*(const f32x4*)p1, *(const f32x4*)(p1+4), hv, lv);
    *(bf16x8*)((char*)inH1 + ur*512     + ((uc*16) ^ ((ur&7)<<4))) = hv;
    *(bf16x8*)((char*)inH1 + (ur+8)*512 + ((uc*16) ^ ((ur&7)<<4))) = lv;
    const float* p2 = h2ig + (size_t)(gp*GR + ur)*HD + uc*8;
    split8(*(const f32x4*)p2, *(const f32x4*)(p2+4), hv, lv);
    *(bf16x8*)((char*)inH2 + ur*512     + ((uc*16) ^ ((ur&7)<<4))) = hv;
    *(bf16x8*)((char*)inH2 + (ur+8)*512 + ((uc*16) ^ ((ur&7)<<4))) = lv;
    h1own[uc][ur] = h1ig[(size_t)(gp*GR+ur)*HD + rz + uc];
    h2own[uc][ur] = h2ig[(size_t)(gp*GR+ur)*HD + rz + uc];
  }
  const int xr = tid >> 4, xf = tid & 15;
  const int xrl = xr & 7;                   // clamped row: ALL threads load (uniform vmcnt)
  if (xr < 8){
    const float* px = xg + ((size_t)(gp*GR + xr)*NT + 0)*FB + xf*8;
    bf16x8 hv, lv;
    split8(*(const f32x4*)px, *(const f32x4*)(px+4), hv, lv);
    *(bf16x8*)((char*)inX + xr*256     + ((xf*16) ^ ((xr&7)<<4))) = hv;
    *(bf16x8*)((char*)inX + (xr+8)*256 + ((xf*16) ^ ((xr&7)<<4))) = lv;
  }
  __syncthreads();   // full drain at init boundary (intentional)

  // ---- prologue: acc1 = L1(0) = W1·[x(0); h1(0)] ----
  f32x4 acc1 = {0.f,0.f,0.f,0.f};
#pragma unroll
  for (int j = 0; j < 4; ++j){
    bf16x8 fx = *(bf16x8*)((char*)inX + ln*256 + ((j*64 + lk*16) ^ ((ln&7)<<4)));
    acc1 = __builtin_amdgcn_mfma_f32_16x16x32_bf16(w1f[j], fx, acc1, 0, 0, 0);
  }
#pragma unroll
  for (int j = 0; j < 8; ++j){
    bf16x8 fh = *(bf16x8*)((char*)inH1 + ln*512 + ((j*64 + lk*16) ^ ((ln&7)<<4)));
    acc1 = __builtin_amdgcn_mfma_f32_16x16x32_bf16(w1f[4+j], fh, acc1, 0, 0, 0);
  }

  for (int t = 0; t < NT; ++t){
    unsigned* h1s = h1buf + (unsigned)(t & 1)*131072u + (unsigned)(gp*GR)*512u;
    unsigned* h2s = h2buf + (unsigned)(t & 1)*131072u + (unsigned)(gp*GR)*512u;
    unsigned* h2r = h2buf + (unsigned)((t + 1) & 1)*131072u + (unsigned)(gp*GR)*512u;
    const bool notlast = (t + 1) < NT;   // block-uniform

    // issue h2(t-1) gather loads (epoch t) — consumed after A1
    u32x4 g2a, g2b, g2c, g2d;
    if (t > 0) ISSUE_G8(&h2r[ur*512 + uc*16], g2a, g2b, g2c, g2d);

    // ---- A1: finish h1(t) ----
#pragma unroll
    for (int r4 = 0; r4 < 4; ++r4)
      aldsA[wv*16 + lk*4 + r4][ln] = acc1[r4];   // C/D: row=(lane>>4)*4+reg, col=lane&15
    BARRIER();
    {
      float az = aldsA[uc][ur]    + aldsA[uc][ur+8]    + b1s[uc];
      float ac = aldsA[32+uc][ur] + aldsA[32+uc][ur+8] + b1s[32+uc];
      float z  = 0.5f*(az/(1.0f+fabsf(az)) + 1.0f);
      float cd = ac/(1.0f+fabsf(ac));
      float hn = z*h1own[uc][ur] + (1.0f - z)*cd;
      h1own[uc][ur] = hn;
      short hb = f2bf(hn), lb = f2bf(hn - bf2f(hb));
      st_msg(&h1s[ur*512 + (rz + uc)*2], hb, lb, (unsigned)(t+1));
    }

    // consume h2(t-1): outstanding [prev stH2?, prev outg?, g2 x4, stH1] -> vmcnt(1)
    // retires everything older, leaves only stH1; g2 complete (count-based, uniform)
    if (t > 0){
      WAITV4(1, g2a, g2b, g2c, g2d);
      bf16x8 hv, lv;
      if (!chk_unpack(g2a, g2b, g2c, g2d, (unsigned)t, hv, lv))
        gather8(&h2r[ur*512 + uc*16], (unsigned)t, hv, lv);
      *(bf16x8*)((char*)inH2 + ur*512     + ((uc*16) ^ ((ur&7)<<4))) = hv;
      *(bf16x8*)((char*)inH2 + (ur+8)*512 + ((uc*16) ^ ((ur&7)<<4))) = lv;
    }
    BARRIER();   // inH2 visible

    // ---- A-window: fh2 frags once -> L2-h2half ----
    bf16x8 fh2[8];
#pragma unroll
    for (int j = 0; j < 8; ++j)
      fh2[j] = *(bf16x8*)((char*)inH2 + ln*512 + ((j*64 + lk*16) ^ ((ln&7)<<4)));
    f32x4 acc2 = {0.f,0.f,0.f,0.f};
#pragma unroll
    for (int j = 0; j < 8; ++j)
      acc2 = __builtin_amdgcn_mfma_f32_16x16x32_bf16(w2f[8+j], fh2[j], acc2, 0, 0, 0);

    // issue h1(t) gather NOW (~0.3us after peer stores -> samples fresh data);
    // head(t-1) below covers the return flight. x-loads by ALL threads (uniform vmcnt).
    u32x4 g1a, g1b, g1c, g1d;
    ISSUE_G8(&h1s[ur*512 + uc*16], g1a, g1b, g1c, g1d);
    f32x4 xa = {0,0,0,0}, xb = {0,0,0,0};
    if (notlast){
      const float* px = xg + ((size_t)(gp*GR + xrl)*NT + (t+1))*FB + xf*8;
      ISSUE_X2(px, xa, xb);
    }

    // head(t-1) for batch row gp*GR+sb
    float outv = 0.f; bool dow = false; size_t oaddr = 0;
    if (t > 0){
      f32x4 acc3a = {0,0,0,0}, acc3b = {0,0,0,0};
#pragma unroll
      for (int j = 0; j < 8; ++j){
        acc3a = __builtin_amdgcn_mfma_f32_16x16x32_bf16(w3f[0][j], fh2[j], acc3a, 0, 0, 0);
        acc3b = __builtin_amdgcn_mfma_f32_16x16x32_bf16(w3f[1][j], fh2[j], acc3b, 0, 0, 0);
      }
      if (ln == sb){
#pragma unroll
        for (int r4 = 0; r4 < 4; ++r4){
          int d0 = wv*32 + lk*4 + r4;
          h3p[d0] = acc3a[r4]; h3p[d0+16] = acc3b[r4];
        }
      }
      if (ln == sb + 8){
#pragma unroll
        for (int r4 = 0; r4 < 4; ++r4){
          int d0 = wv*32 + lk*4 + r4;
          h3q[d0] = acc3a[r4]; h3q[d0+16] = acc3b[r4];
        }
      }
      BARRIER();
      if (tid < 128) h3row[tid] = fmaxf(h3p[tid] + h3q[tid] + b3L[tid], 0.0f);
      BARRIER();
      if (wv == 0){
        const int l = tid, c = l >> 2, kq = l & 3;
        float p = 0.f;
        if (c < 10){
          const float* wr = &W4L[c*134 + kq*33];
          const float* hr = &h3row[kq*32];
#pragma unroll
          for (int k = 0; k < 32; ++k) p += wr[k]*hr[k];
        }
        p += __shfl_xor(p, 1, 4);
        p += __shfl_xor(p, 2, 4);
        if (c < 10 && kq == 0) ytmp[c] = p + b4L[c];
        asm volatile("s_waitcnt lgkmcnt(0)" ::: "memory");
        float yv = (l < 10) ? ytmp[l] : -INFINITY;
        float mx = yv;
#pragma unroll
        for (int off = 1; off < 16; off <<= 1)
          mx = fmaxf(mx, __shfl_xor(mx, off, 16));
        float ex = (l < 10) ? expf(yv - mx) : 0.0f;
        float sm = ex;
#pragma unroll
        for (int off = 1; off < 16; off <<= 1)
          sm += __shfl_xor(sm, off, 16);
        if (l < 10){
          outv = yv - (mx + logf(sm));
          dow = true;
          oaddr = ((size_t)(gp*GR + sb)*NT + (t-1))*NC + l;
        }
      }
    }

    // consume h1(t): outstanding [stH1, g1 x4, x x2?] -> vmcnt(2) leaves x x2 (uniform);
    // last step has no x -> vmcnt(0)
    {
      if (notlast) WAITV4(2, g1a, g1b, g1c, g1d);
      else         WAITV4(0, g1a, g1b, g1c, g1d);
      bf16x8 hv, lv;
      if (!chk_unpack(g1a, g1b, g1c, g1d, (unsigned)(t+1), hv, lv))
        gather8(&h1s[ur*512 + uc*16], (unsigned)(t+1), hv, lv);
      *(bf16x8*)((char*)inH1 + ur*512     + ((uc*16) ^ ((ur&7)<<4))) = hv;
      *(bf16x8*)((char*)inH1 + (ur+8)*512 + ((uc*16) ^ ((ur&7)<<4))) = lv;
    }
    if (dow) outg[oaddr] = outv;   // deferred: keeps vmcnt counts uniform at the waits above
    BARRIER();   // inH1 visible

    // ---- B: fh1 frags once -> L2-h1half; gate h2 ----
    bf16x8 fh1[8];
#pragma unroll
    for (int j = 0; j < 8; ++j)
      fh1[j] = *(bf16x8*)((char*)inH1 + ln*512 + ((j*64 + lk*16) ^ ((ln&7)<<4)));
#pragma unroll
    for (int j = 0; j < 8; ++j)
      acc2 = __builtin_amdgcn_mfma_f32_16x16x32_bf16(w2f[j], fh1[j], acc2, 0, 0, 0);
#pragma unroll
    for (int r4 = 0; r4 < 4; ++r4)
      aldsB[wv*16 + lk*4 + r4][ln] = acc2[r4];
    BARRIER();
    {
      float az = aldsB[uc][ur]    + aldsB[uc][ur+8]    + b2s[uc];
      float ac = aldsB[32+uc][ur] + aldsB[32+uc][ur+8] + b2s[32+uc];
      float z  = 0.5f*(az/(1.0f+fabsf(az)) + 1.0f);
      float cd = ac/(1.0f+fabsf(ac));
      float hn = z*h2own[uc][ur] + (1.0f - z)*cd;
      h2own[uc][ur] = hn;
      short hb = f2bf(hn), lb = f2bf(hn - bf2f(hb));
      st_msg(&h2s[ur*512 + (rz + uc)*2], hb, lb, (unsigned)(t+1));
    }

    // consume x(t+1): outstanding [x x2, outg?, stH2] -> vmcnt(1) leaves stH2 (uniform)
    if (notlast){
      WAITV2(1, xa, xb);
      if (xr < 8){
        bf16x8 hv, lv;
        split8(xa, xb, hv, lv);
        *(bf16x8*)((char*)inX + xr*256     + ((xf*16) ^ ((xr&7)<<4))) = hv;
        *(bf16x8*)((char*)inX + (xr+8)*256 + ((xf*16) ^ ((xr&7)<<4))) = lv;
      }
      BARRIER();   // inX visible

      // ---- B-window: L1(t+1) = x-part (LDS) + h1-part (fh1 regs, reused) ----
      f32x4 a1n = {0.f,0.f,0.f,0.f};
#pragma unroll
      for (int j = 0; j < 4; ++j){
        bf16x8 fx = *(bf16x8*)((char*)inX + ln*256 + ((j*64 + lk*16) ^ ((ln&7)<<4)));
        a1n = __builtin_amdgcn_mfma_f32_16x16x32_bf16(w1f[j], fx, a1n, 0, 0, 0);
      }
#pragma unroll
      for (int j = 0; j < 8; ++j)
        a1n = __builtin_amdgcn_mfma_f32_16x16x32_bf16(w1f[4+j], fh1[j], a1n, 0, 0, 0);
      acc1 = a1n;
    }
  }

  // ---- epilogue: gather h2(NT-1) (epoch NT), head(NT-1) ----
  {
    unsigned* h2e = h2buf + (unsigned)((NT-1) & 1)*131072u + (unsigned)(gp*GR)*512u;
    bf16x8 hv, lv;
    gather8(&h2e[ur*512 + uc*16], (unsigned)NT, hv, lv);
    *(bf16x8*)((char*)inH2 + ur*512     + ((uc*16) ^ ((ur&7)<<4))) = hv;
    *(bf16x8*)((char*)inH2 + (ur+8)*512 + ((uc*16) ^ ((ur&7)<<4))) = lv;
  }
  BARRIER();
  {
    bf16x8 fh2[8];
#pragma unroll
    for (int j = 0; j < 8; ++j)
      fh2[j] = *(bf16x8*)((char*)inH2 + ln*512 + ((j*64 + lk*16) ^ ((ln&7)<<4)));
    f32x4 acc3a = {0,0,0,0}, acc3b = {0,0,0,0};
#pragma unroll
    for (int j = 0; j < 8; ++j){
      acc3a = __builtin_amdgcn_mfma_f32_16x16x32_bf16(w3f[0][j], fh2[j], acc3a, 0, 0, 0);
      acc3b = __builtin_amdgcn_mfma_f32_16x16x32_bf16(w3f[1][j], fh2[j], acc3b, 0, 0, 0);
    }
    if (ln == sb){
#pragma unroll
      for (int r4 = 0; r4 < 4; ++r4){
        int d0 = wv*32 + lk*4 + r4;
        h3p[d0] = acc3a[r4]; h3p[d0+16] = acc3b[r4];
      }
    }
    if (ln == sb + 8){
#pragma unroll
      for (int r4 = 0; r4 < 4; ++r4){
        int d0 = wv*32 + lk*4 + r4;
        h3q[d0] = acc3a[r4]; h3q[d0+16] = acc3b[r4];
      }
    }
    BARRIER();
    if (tid < 128) h3row[tid] = fmaxf(h3p[tid] + h3q[tid] + b3L[tid], 0.0f);
    BARRIER();
    if (wv == 0){
      const int l = tid, c = l >> 2, kq = l & 3;
      float p = 0.f;
      if (c < 10){
        const float* wr = &W4L[c*134 + kq*33];
        const float* hr = &h3row[kq*32];
#pragma unroll
        for (int k = 0; k < 32; ++k) p += wr[k]*hr[k];
      }
      p += __shfl_xor(p, 1, 4);
      p += __shfl_xor(p, 2, 4);
      if (c < 10 && kq == 0) ytmp[c] = p + b4L[c];
      asm volatile("s_waitcnt lgkmcnt(0)" ::: "memory");
      float yv = (l < 10) ? ytmp[l] : -INFINITY;
      float mx = yv;
#pragma unroll
      for (int off = 1; off < 16; off <<= 1)
        mx = fmaxf(mx, __shfl_xor(mx, off, 16));
      float ex = (l < 10) ? expf(yv - mx) : 0.0f;
      float sm = ex;
#pragma unroll
      for (int off = 1; off < 16; off <<= 1)
        sm += __shfl_xor(sm, off, 16);
      if (l < 10)
        outg[((size_t)(gp*GR + sb)*NT + (NT-1))*NC + l] = yv - (mx + logf(sm));
    }
  }
}

extern "C" void kernel_launch(void* const* d_in, const int* in_sizes, int n_in,
                              void* d_out, int out_size, void* d_ws, size_t ws_size,
                              hipStream_t stream) {
  const float* xg  = (const float*)d_in[0];
  const float* h1i = (const float*)d_in[1];
  const float* h2i = (const float*)d_in[2];
  const float* W1  = (const float*)d_in[3];
  const float* b1  = (const float*)d_in[4];
  const float* W2  = (const float*)d_in[5];
  const float* b2  = (const float*)d_in[6];
  const float* W3  = (const float*)d_in[7];
  const float* b3  = (const float*)d_in[8];
  const float* W4  = (const float*)d_in[9];
  const float* b4  = (const float*)d_in[10];
  float* out = (float*)d_out;
  float* ws  = (float*)d_ws;

  // clear all message epochs (stale epochs from a previous replay would falsely validate)
  hipMemsetAsync(d_ws, 0, 2u * 1024u * 1024u, stream);

  egru_persistent<<<dim3(256), dim3(256), 0, stream>>>(
      xg, h1i, h2i, W1, b1, W2, b2, W3, b3, W4, b4, out, ws);
}